// Round 8
// baseline (299.759 us; speedup 1.0000x reference)
//
#include <hip/hip_runtime.h>

#define NBUCK 512          // node buckets of 256: bucket = id >> 8
#define SCAT_BLOCKS 256

static inline int cdiv_h(int a, int b) { return (a + b - 1) / b; }

// ---------------- kernels ----------------

__global__ void k_zero_i(int* p, int n) {
    int i = blockIdx.x * blockDim.x + threadIdx.x;
    if (i < n) p[i] = 0;
}

// both bucket histograms (dst-key and src-key) in one pass
__global__ void k_bhist2(const int* src, const int* dst, int* totD, int* totS, int E) {
    __shared__ int sh[1024];
    int t = threadIdx.x;                 // 512 threads
    sh[t] = 0; sh[t + 512] = 0;
    __syncthreads();
    for (int e = blockIdx.x * blockDim.x + t; e < E; e += gridDim.x * blockDim.x) {
        atomicAdd(&sh[dst[e] >> 8], 1);
        atomicAdd(&sh[512 + (src[e] >> 8)], 1);
    }
    __syncthreads();
    int c0 = sh[t], c1 = sh[512 + t];
    if (c0) atomicAdd(&totD[t], c0);
    if (c1) atomicAdd(&totS[t], c1);
}

// dual exclusive scan: blockIdx 0 -> D arrays, 1 -> S arrays
__global__ void k_bscan(const int* totD, const int* totS,
                        int* baseD, int* curD, int* baseS, int* curS) {
    const int* tot = blockIdx.x ? totS : totD;
    int* base = blockIdx.x ? baseS : baseD;
    int* cur  = blockIdx.x ? curS  : curD;
    __shared__ int sh[NBUCK];
    int t = threadIdx.x;
    int v = tot[t];
    sh[t] = v;
    __syncthreads();
    for (int off = 1; off < NBUCK; off <<= 1) {
        int a = (t >= off) ? sh[t - off] : 0;
        __syncthreads();
        sh[t] += a;
        __syncthreads();
    }
    int excl = sh[t] - v;
    base[t] = excl;
    cur[t] = excl;
    if (t == NBUCK - 1) base[NBUCK] = sh[t];
}

// partition edges by dst-bucket: packed = (dst&255)<<24 | src
__global__ void k_bscatD(const int* src, const int* dst, int* cursor,
                         int* packed, int E, int chunk) {
    __shared__ int shc[NBUCK], cur[NBUCK];
    int t = threadIdx.x;                 // 512 threads
    shc[t] = 0;
    __syncthreads();
    int e0 = blockIdx.x * chunk, e1 = min(E, e0 + chunk);
    for (int e = e0 + t; e < e1; e += 512) atomicAdd(&shc[dst[e] >> 8], 1);
    __syncthreads();
    int c = shc[t];
    if (c) cur[t] = atomicAdd(&cursor[t], c);
    __syncthreads();
    for (int e = e0 + t; e < e1; e += 512) {
        int d = dst[e];
        int off = atomicAdd(&cur[d >> 8], 1);
        packed[off] = ((d & 255) << 24) | src[e];
    }
}

// partition edges by src-bucket: packed = (src&255)<<24 | dst
__global__ void k_bscatS(const int* src, const int* dst, int* cursor,
                         int* packed, int E, int chunk) {
    __shared__ int shc[NBUCK], cur[NBUCK];
    int t = threadIdx.x;                 // 512 threads
    shc[t] = 0;
    __syncthreads();
    int e0 = blockIdx.x * chunk, e1 = min(E, e0 + chunk);
    for (int e = e0 + t; e < e1; e += 512) atomicAdd(&shc[src[e] >> 8], 1);
    __syncthreads();
    int c = shc[t];
    if (c) cur[t] = atomicAdd(&cursor[t], c);
    __syncthreads();
    for (int e = e0 + t; e < e1; e += 512) {
        int s = src[e];
        int off = atomicAdd(&cur[s >> 8], 1);
        packed[off] = ((s & 255) << 24) | dst[e];
    }
}

// per dst-bucket: degree histogram (LDS) -> dinv, u
__global__ void k_bucket1(const int* baseD, const int* packed, const float* x,
                          float* dinv, float* u, int N) {
    __shared__ int c256[256];
    const int b = blockIdx.x, t = threadIdx.x;
    const int eb = baseD[b], ee = baseD[b + 1];
    c256[t] = 0;
    __syncthreads();
    for (int e = eb + t; e < ee; e += 256)
        atomicAdd(&c256[((unsigned)packed[e]) >> 24], 1);
    __syncthreads();
    int i = b * 256 + t;
    if (i < N) {
        float dv = rsqrtf(1.f + (float)c256[t]);
        dinv[i] = dv;
        u[i] = dv * x[i];
    }
}

// M = W2 @ Wf  (64x16); bb = b2 @ Wf + bf  (16)
__global__ void k_Mbb(const float* W2, const float* Wf, const float* b2, const float* bf,
                      float* M, float* bb) {
    int t = threadIdx.x;           // single block of 1024
    int f = t >> 4, o = t & 15;
    float a = 0.f;
    for (int k = 0; k < 64; ++k) a = fmaf(W2[f * 64 + k], Wf[k * 16 + o], a);
    M[t] = a;
    if (t < 16) {
        float c = 0.f;
        for (int k = 0; k < 64; ++k) c = fmaf(b2[k], Wf[k * 16 + t], c);
        bb[t] = c + bf[t];
    }
}

// per dst-bucket: s-accumulate (LDS atomics, u gathers are 4B L2 hits),
// then per node MLP: zd = dinv * (relu(s*W1+b1) @ M)
__global__ void k_bucket2(const int* baseD, const int* packed,
                          const float* dinv, const float* u,
                          const float* W1, const float* b1, const float* M,
                          float* zd, int N) {
    __shared__ float sacc[256];
    __shared__ float sW1[64], sb1[64], sM[1024];
    const int b = blockIdx.x, t = threadIdx.x;
    if (t < 64) { sW1[t] = W1[t]; sb1[t] = b1[t]; }
    for (int j = t; j < 1024; j += 256) sM[j] = M[j];
    sacc[t] = 0.f;
    __syncthreads();
    const int eb = baseD[b], ee = baseD[b + 1];
    int e = eb + t;
    for (; e + 512 < ee; e += 768) {     // 3-deep manual pipeline (independent gathers)
        int pk0 = packed[e], pk1 = packed[e + 256], pk2 = packed[e + 512];
        float v0 = u[pk0 & 0xFFFFFF];
        float v1 = u[pk1 & 0xFFFFFF];
        float v2 = u[pk2 & 0xFFFFFF];
        atomicAdd(&sacc[((unsigned)pk0) >> 24], v0);
        atomicAdd(&sacc[((unsigned)pk1) >> 24], v1);
        atomicAdd(&sacc[((unsigned)pk2) >> 24], v2);
    }
    for (; e < ee; e += 256) {
        int pk = packed[e];
        atomicAdd(&sacc[((unsigned)pk) >> 24], u[pk & 0xFFFFFF]);
    }
    __syncthreads();
    int i = b * 256 + t;
    if (i >= N) return;
    float dv = dinv[i];
    float s = dv * (u[i] + sacc[t]);
    float za[16];
#pragma unroll
    for (int o = 0; o < 16; ++o) za[o] = 0.f;
    for (int f = 0; f < 64; ++f) {
        float hf = fmaxf(fmaf(s, sW1[f], sb1[f]), 0.f);
#pragma unroll
        for (int o = 0; o < 16; ++o) za[o] = fmaf(hf, sM[f * 16 + o], za[o]);
    }
#pragma unroll
    for (int o = 0; o < 16; ++o) zd[i * 16 + o] = dv * za[o];
}

// layer-2 edge sweep over src-bucketed edges: zd reads bucket-local (cache-hot),
// dinv/batch lookups are 4B L2 hits, accumulate into LDS gsum, flush coalesced atomics.
__global__ void k_sweep(const int* baseS, const int* packed, const int* batch,
                        const float* dinv, const float* zd, float* gsum) {
    __shared__ float lg[NBUCK * 16];     // 32 KB: per-block private gsum
    const int t = threadIdx.x;           // 512 threads
    for (int j = t; j < NBUCK * 16; j += 512) lg[j] = 0.f;
    __syncthreads();
    const int gidx = t >> 4, o = t & 15; // 32 edge-groups of 16 lanes
    for (int bb = 0; bb < 2; ++bb) {
        const int b = blockIdx.x * 2 + bb;
        const int srcBase = b << 8;
        const int e0 = baseS[b], e1 = baseS[b + 1];
        int p = e0 + gidx;
        for (; p + 32 < e1; p += 64) {   // 2-deep pipeline
            int pk0 = packed[p], pk1 = packed[p + 32];
            int d0 = pk0 & 0xFFFFFF, d1 = pk1 & 0xFFFFFF;
            float w0 = dinv[d0], w1 = dinv[d1];
            int g0 = batch[d0], g1 = batch[d1];
            float v0 = zd[((srcBase + (((unsigned)pk0) >> 24)) << 4) + o];
            float v1 = zd[((srcBase + (((unsigned)pk1) >> 24)) << 4) + o];
            atomicAdd(&lg[(g0 << 4) + o], w0 * v0);
            atomicAdd(&lg[(g1 << 4) + o], w1 * v1);
        }
        for (; p < e1; p += 32) {
            int pk = packed[p];
            int d = pk & 0xFFFFFF;
            float w = dinv[d];
            int g = batch[d];
            float v = zd[((srcBase + (((unsigned)pk) >> 24)) << 4) + o];
            atomicAdd(&lg[(g << 4) + o], w * v);
        }
    }
    __syncthreads();
    for (int j = t; j < NBUCK * 16; j += 512)
        atomicAdd(&gsum[j], lg[j]);      // coalesced line-RMWs
}

// self-loop term + graph node counts: block = 16 consecutive nodes x 16 lanes
__global__ void k_selfpool(const int* batch, const float* dinv, const float* zd,
                           float* gsum, float* cntf, int N) {
    const int t = threadIdx.x, o = t & 15, row = t >> 4;
    const int i0 = blockIdx.x * 16;
    const int i = i0 + row;
    const bool valid = i < N;
    float v = 0.f;
    int g = 0;
    if (valid) { g = batch[i]; v = dinv[i] * zd[i * 16 + o]; }

    __shared__ int s_g0, s_g1, s_nvalid;
    if (t == 0) {
        s_g0 = batch[i0];
        int ilast = min(i0 + 15, N - 1);
        s_g1 = batch[ilast];
        s_nvalid = min(N - i0, 16);
    }
    __shared__ float red[16][17];
    red[row][o] = v;
    __syncthreads();

    if (s_g0 == s_g1) {
        if (t < 16) {
            float a = 0.f;
#pragma unroll
            for (int r = 0; r < 16; ++r) a += red[r][t];
            atomicAdd(&gsum[s_g0 * 16 + t], a);
            if (t == 0) atomicAdd(&cntf[s_g0], (float)s_nvalid);
        }
    } else {
        if (valid) {
            atomicAdd(&gsum[g * 16 + o], v);
            if (o == 0) atomicAdd(&cntf[g], 1.0f);
        }
    }
}

__global__ void k_final(const float* gsum, const float* cntf, const float* bb,
                        float* out, int G) {
    int t = blockIdx.x * blockDim.x + threadIdx.x;
    int g = t >> 4, o = t & 15;
    if (g >= G) return;
    out[t] = gsum[t] / fmaxf(cntf[g], 1.0f) + bb[o];
}

// ---------------- launch ----------------

extern "C" void kernel_launch(void* const* d_in, const int* in_sizes, int n_in,
                              void* d_out, int out_size, void* d_ws, size_t ws_size,
                              hipStream_t stream) {
    const float* x   = (const float*)d_in[0];
    const int*   ei  = (const int*)d_in[1];   // [2,E]: src then dst
    const int*   bat = (const int*)d_in[2];
    const float* W1  = (const float*)d_in[4];
    const float* b1  = (const float*)d_in[5];
    const float* W2  = (const float*)d_in[6];
    const float* b2  = (const float*)d_in[7];
    const float* Wf  = (const float*)d_in[8];
    const float* bf  = (const float*)d_in[9];
    float* out = (float*)d_out;

    const int N = in_sizes[0];        // Fin = 1
    const int E = in_sizes[1] / 2;
    const int G = out_size / 16;
    const int NB = cdiv_h(N, 256);    // dst/src buckets in use (<= NBUCK)

    const int* src = ei;
    const int* dst = ei + E;

    // workspace layout (4B elems); packed is time-shared (D-partition, then S-partition)
    char* w = (char*)d_ws;
    int*   packed = (int*)w;            w += (size_t)E * 4;
    float* zd     = (float*)w;          w += (size_t)16 * N * 4;
    float* dinv   = (float*)w;          w += (size_t)N * 4;
    float* u      = (float*)w;          w += (size_t)N * 4;
    int*   baseD  = (int*)w;            w += (NBUCK + 1) * 4;
    int*   curD   = (int*)w;            w += NBUCK * 4;
    int*   baseS  = (int*)w;            w += (NBUCK + 1) * 4;
    int*   curS   = (int*)w;            w += NBUCK * 4;
    // contiguous zero region: totD | totS | gsum | cntf
    int*   totD   = (int*)w;            w += NBUCK * 4;
    int*   totS   = (int*)w;            w += NBUCK * 4;
    float* gsum   = (float*)w;          w += (size_t)16 * G * 4;
    float* cntf   = (float*)w;          w += (size_t)G * 4;
    float* M      = (float*)w;          w += 1024 * 4;
    float* bb     = (float*)w;

    const int nzero = NBUCK + NBUCK + 16 * G + G;
    const int chunk = cdiv_h(E, SCAT_BLOCKS);

    // 0) zero counters/accumulators
    k_zero_i<<<cdiv_h(nzero, 256), 256, 0, stream>>>(totD, nzero);

    // 1) both bucket histograms, one pass
    k_bhist2<<<256, 512, 0, stream>>>(src, dst, totD, totS, E);

    // 2) dual scan -> base/cursor for D and S
    k_bscan<<<2, NBUCK, 0, stream>>>(totD, totS, baseD, curD, baseS, curS);

    // 3) dst-partition; 4) per-bucket degree -> dinv,u
    k_bscatD<<<SCAT_BLOCKS, 512, 0, stream>>>(src, dst, curD, packed, E, chunk);
    k_bucket1<<<NB, 256, 0, stream>>>(baseD, packed, x, dinv, u, N);

    // 5) folded weights
    k_Mbb<<<1, 1024, 0, stream>>>(W2, Wf, b2, bf, M, bb);

    // 6) layer-1 (fused s-accumulate + MLP) -> zd
    k_bucket2<<<NB, 256, 0, stream>>>(baseD, packed, dinv, u, W1, b1, M, zd, N);

    // 7) src-partition (re-uses packed; kB2 has consumed the D-partition)
    k_bscatS<<<SCAT_BLOCKS, 512, 0, stream>>>(src, dst, curS, packed, E, chunk);

    // 8) layer-2 sweep into LDS-private gsum
    k_sweep<<<NBUCK / 2, 512, 0, stream>>>(baseS, packed, bat, dinv, zd, gsum);

    // 9) self-loop term + counts; 10) finalize
    k_selfpool<<<cdiv_h(N, 16), 256, 0, stream>>>(bat, dinv, zd, gsum, cntf, N);
    k_final<<<cdiv_h(G * 16, 256), 256, 0, stream>>>(gsum, cntf, bb, out, G);
}

// Round 9
// 138.484 us; speedup vs baseline: 2.1646x; 2.1646x over previous
//
#include <hip/hip_runtime.h>
#include <hip/hip_fp16.h>

#define TPB 256
#define NBUCK 512          // buckets of 256 nodes: bucket = dst >> 8
#define A2_BLOCKS 400

// ---------------- kernels ----------------

__global__ void k_zero_i(int* p, int n) {
    int i = blockIdx.x * blockDim.x + threadIdx.x;
    if (i < n) p[i] = 0;
}

__global__ void k_zero_f(float* p, int n) {
    int i = blockIdx.x * blockDim.x + threadIdx.x;
    if (i < n) p[i] = 0.f;
}

// A0: bucket histogram, LDS-privatized; ~131K global atomics total
__global__ void k_bhistA(const int* dst, int* bucketTot, int E) {
    __shared__ int sh[NBUCK];
    int t = threadIdx.x;
    sh[t] = 0; sh[t + 256] = 0;
    __syncthreads();
    for (int e = blockIdx.x * blockDim.x + t; e < E; e += gridDim.x * blockDim.x)
        atomicAdd(&sh[dst[e] >> 8], 1);
    __syncthreads();
    int c0 = sh[t], c1 = sh[t + 256];
    if (c0) atomicAdd(&bucketTot[t], c0);
    if (c1) atomicAdd(&bucketTot[t + 256], c1);
}

// A1: exclusive scan of 512 bucket totals -> base; init cursor
__global__ void k_bscan(const int* tot, int* base, int* cursor) {
    __shared__ int sh[NBUCK];
    int t = threadIdx.x;
    int v = tot[t];
    sh[t] = v;
    __syncthreads();
    for (int off = 1; off < NBUCK; off <<= 1) {
        int a = (t >= off) ? sh[t - off] : 0;
        __syncthreads();
        sh[t] += a;
        __syncthreads();
    }
    int excl = sh[t] - v;
    base[t] = excl;
    cursor[t] = excl;
    if (t == NBUCK - 1) base[NBUCK] = sh[t];
}

// A2: partition edges into bucket-contiguous regions as packed words
// word = (dst & 255) << 24 | src
__global__ void k_bscatter(const int* src, const int* dst, int* bucketCursor,
                           int* packed, int E, int chunk) {
    __shared__ int shc[NBUCK];
    __shared__ int cur[NBUCK];
    int t = threadIdx.x;
    shc[t] = 0; shc[t + 256] = 0;
    __syncthreads();
    int e0 = blockIdx.x * chunk;
    int e1 = min(E, e0 + chunk);
    for (int e = e0 + t; e < e1; e += 256)
        atomicAdd(&shc[dst[e] >> 8], 1);
    __syncthreads();
    int c0 = shc[t], c1 = shc[t + 256];
    if (c0) cur[t] = atomicAdd(&bucketCursor[t], c0);
    if (c1) cur[t + 256] = atomicAdd(&bucketCursor[t + 256], c1);
    __syncthreads();
    for (int e = e0 + t; e < e1; e += 256) {
        int d = dst[e];
        int b = d >> 8;
        int off = atomicAdd(&cur[b], 1);
        packed[off] = ((d & 255) << 24) | src[e];
    }
}

// B: per-bucket counting sort -> cnt, rowStart, dinv, u, csr (one wg per bucket)
__global__ void k_bucket_csr(const int* bucketBase, const int* packed, const float* x,
                             int* cnt, int* rowStart, float* dinv, float* u,
                             int* csr, int N) {
    __shared__ int c256[256];
    __shared__ int row256[256];
    __shared__ int cur256[256];
    const int b = blockIdx.x;
    const int t = threadIdx.x;
    const int nodeBase = b * 256;
    const int nodeCnt = min(N - nodeBase, 256);
    const int eb = bucketBase[b], ee = bucketBase[b + 1];

    c256[t] = 0;
    __syncthreads();
    for (int e = eb + t; e < ee; e += 256)
        atomicAdd(&c256[((unsigned)packed[e]) >> 24], 1);
    __syncthreads();

    int v = c256[t];
    row256[t] = v;
    __syncthreads();
    for (int off = 1; off < 256; off <<= 1) {
        int a = (t >= off) ? row256[t - off] : 0;
        __syncthreads();
        row256[t] += a;
        __syncthreads();
    }
    int excl = row256[t] - v;
    cur256[t] = excl;
    __syncthreads();

    if (t < nodeCnt) {
        int i = nodeBase + t;
        cnt[i] = v;
        rowStart[i] = eb + excl;
        float dv = rsqrtf(1.f + (float)v);
        dinv[i] = dv;
        u[i] = dv * x[i];
    }

    for (int e = eb + t; e < ee; e += 256) {
        int w = packed[e];
        int local = ((unsigned)w) >> 24;
        int s = w & 0x00FFFFFF;
        int off = atomicAdd(&cur256[local], 1);
        csr[eb + off] = s;
    }
}

// M = W2 @ Wf  (64x16); bb = b2 @ Wf + bf  (16)
__global__ void k_Mbb(const float* W2, const float* Wf, const float* b2, const float* bf,
                      float* M, float* bb) {
    int t = threadIdx.x;           // single block of 1024
    int f = t >> 4, o = t & 15;
    float a = 0.f;
    for (int k = 0; k < 64; ++k) a = fmaf(W2[f * 64 + k], Wf[k * 16 + o], a);
    M[t] = a;
    if (t < 16) {
        float c = 0.f;
        for (int k = 0; k < 64; ++k) c = fmaf(b2[k], Wf[k * 16 + t], c);
        bb[t] = c + bf[t];
    }
}

// per node: s-gather over CSR (8-deep MLP) + layer-1 + fold; zd stored as half2
__global__ void k_node(const int* rowStart, const int* cnt, const int* csr,
                       const float* u, const float* dinv,
                       const float* W1, const float* b1, const float* M,
                       __half2* zd, int N) {
    __shared__ float sW1[64], sb1[64], sM[1024];
    int t = threadIdx.x;
    if (t < 64) { sW1[t] = W1[t]; sb1[t] = b1[t]; }
    for (int j = t; j < 1024; j += blockDim.x) sM[j] = M[j];
    __syncthreads();
    int i = blockIdx.x * blockDim.x + t;
    if (i >= N) return;
    float dv = dinv[i];
    int rs = rowStart[i], dg = cnt[i];
    float a0 = u[i], a1 = 0.f, a2 = 0.f, a3 = 0.f;
    float a4 = 0.f, a5 = 0.f, a6 = 0.f, a7 = 0.f;
    int k = 0;
    for (; k + 8 <= dg; k += 8) {
        int s0 = csr[rs + k],     s1 = csr[rs + k + 1];
        int s2 = csr[rs + k + 2], s3 = csr[rs + k + 3];
        int s4 = csr[rs + k + 4], s5 = csr[rs + k + 5];
        int s6 = csr[rs + k + 6], s7 = csr[rs + k + 7];
        float v0 = u[s0], v1 = u[s1], v2 = u[s2], v3 = u[s3];
        float v4 = u[s4], v5 = u[s5], v6 = u[s6], v7 = u[s7];
        a0 += v0; a1 += v1; a2 += v2; a3 += v3;
        a4 += v4; a5 += v5; a6 += v6; a7 += v7;
    }
    for (; k < dg; ++k) a0 += u[csr[rs + k]];
    float s = dv * (((a0 + a1) + (a2 + a3)) + ((a4 + a5) + (a6 + a7)));
    float za[16];
#pragma unroll
    for (int o = 0; o < 16; ++o) za[o] = 0.f;
    for (int f = 0; f < 64; ++f) {
        float hf = fmaxf(fmaf(s, sW1[f], sb1[f]), 0.f);
#pragma unroll
        for (int o = 0; o < 16; ++o) za[o] = fmaf(hf, sM[f * 16 + o], za[o]);
    }
#pragma unroll
    for (int o = 0; o < 8; ++o)
        zd[i * 8 + o] = __floats2half2_rn(dv * za[2 * o], dv * za[2 * o + 1]);
}

// layer-2 gather + mean-pool, fused. Block = 32 nodes x 8 lanes;
// each lane owns an output PAIR via one half2 load per edge (32B rows).
__global__ void k_gather_pool(const int* batch, const int* rowStart, const int* cnt,
                              const int* csr, const __half2* zd, const float* dinv,
                              float* gsum, float* cntf, int N) {
    const int t = threadIdx.x, j = t & 7, row = t >> 3;
    const int i0 = blockIdx.x * 32;
    const int i = i0 + row;
    const bool valid = i < N;
    float vx = 0.f, vy = 0.f;
    int g = 0;
    if (valid) {
        g = batch[i];
        int rs = rowStart[i], dg = cnt[i];
        float2 a0 = __half22float2(zd[i * 8 + j]);   // self-loop seed
        float2 a1 = {0.f, 0.f}, a2 = {0.f, 0.f}, a3 = {0.f, 0.f};
        float2 a4 = {0.f, 0.f}, a5 = {0.f, 0.f}, a6 = {0.f, 0.f}, a7 = {0.f, 0.f};
        int k = 0;
        for (; k + 8 <= dg; k += 8) {
            int s0 = csr[rs + k],     s1 = csr[rs + k + 1];
            int s2 = csr[rs + k + 2], s3 = csr[rs + k + 3];
            int s4 = csr[rs + k + 4], s5 = csr[rs + k + 5];
            int s6 = csr[rs + k + 6], s7 = csr[rs + k + 7];
            float2 h0 = __half22float2(zd[s0 * 8 + j]);
            float2 h1 = __half22float2(zd[s1 * 8 + j]);
            float2 h2 = __half22float2(zd[s2 * 8 + j]);
            float2 h3 = __half22float2(zd[s3 * 8 + j]);
            float2 h4 = __half22float2(zd[s4 * 8 + j]);
            float2 h5 = __half22float2(zd[s5 * 8 + j]);
            float2 h6 = __half22float2(zd[s6 * 8 + j]);
            float2 h7 = __half22float2(zd[s7 * 8 + j]);
            a0.x += h0.x; a0.y += h0.y;  a1.x += h1.x; a1.y += h1.y;
            a2.x += h2.x; a2.y += h2.y;  a3.x += h3.x; a3.y += h3.y;
            a4.x += h4.x; a4.y += h4.y;  a5.x += h5.x; a5.y += h5.y;
            a6.x += h6.x; a6.y += h6.y;  a7.x += h7.x; a7.y += h7.y;
        }
        for (; k < dg; ++k) {
            float2 h = __half22float2(zd[csr[rs + k] * 8 + j]);
            a0.x += h.x; a0.y += h.y;
        }
        float dvv = dinv[i];
        vx = dvv * (((a0.x + a1.x) + (a2.x + a3.x)) + ((a4.x + a5.x) + (a6.x + a7.x)));
        vy = dvv * (((a0.y + a1.y) + (a2.y + a3.y)) + ((a4.y + a5.y) + (a6.y + a7.y)));
    }

    __shared__ int s_g0, s_g1, s_nvalid;
    if (t == 0) {
        s_g0 = batch[i0];
        int ilast = min(i0 + 31, N - 1);
        s_g1 = batch[ilast];
        s_nvalid = min(N - i0, 32);
    }
    __shared__ float red[32][17];
    red[row][2 * j]     = vx;
    red[row][2 * j + 1] = vy;
    __syncthreads();

    if (s_g0 == s_g1) {
        if (t < 16) {
            float a = 0.f;
#pragma unroll
            for (int r = 0; r < 32; ++r) a += red[r][t];
            atomicAdd(&gsum[s_g0 * 16 + t], a);
            if (t == 0) atomicAdd(&cntf[s_g0], (float)s_nvalid);
        }
    } else {
        if (valid) {
            atomicAdd(&gsum[g * 16 + 2 * j],     vx);
            atomicAdd(&gsum[g * 16 + 2 * j + 1], vy);
            if (j == 0) atomicAdd(&cntf[g], 1.0f);
        }
    }
}

__global__ void k_final(const float* gsum, const float* cntf, const float* bb,
                        float* out, int G) {
    int t = blockIdx.x * blockDim.x + threadIdx.x;
    int g = t >> 4, o = t & 15;
    if (g >= G) return;
    out[t] = gsum[t] / fmaxf(cntf[g], 1.0f) + bb[o];
}

// ---------------- launch ----------------

static inline int cdiv(int a, int b) { return (a + b - 1) / b; }

extern "C" void kernel_launch(void* const* d_in, const int* in_sizes, int n_in,
                              void* d_out, int out_size, void* d_ws, size_t ws_size,
                              hipStream_t stream) {
    const float* x   = (const float*)d_in[0];
    const int*   ei  = (const int*)d_in[1];   // [2,E]: src then dst
    const int*   bat = (const int*)d_in[2];
    const float* W1  = (const float*)d_in[4];
    const float* b1  = (const float*)d_in[5];
    const float* W2  = (const float*)d_in[6];
    const float* b2  = (const float*)d_in[7];
    const float* Wf  = (const float*)d_in[8];
    const float* bf  = (const float*)d_in[9];
    float* out = (float*)d_out;

    const int N = in_sizes[0];        // Fin = 1
    const int E = in_sizes[1] / 2;
    const int G = out_size / 16;

    const int* src = ei;
    const int* dst = ei + E;

    // workspace layout. zd (half2, 32B/node) overlays packed (dead after k_bucket_csr).
    char* w = (char*)d_ws;
    int*   bucketTot    = (int*)w;      w += NBUCK * 4;
    int*   bucketBase   = (int*)w;      w += (NBUCK + 1) * 4;
    int*   bucketCursor = (int*)w;      w += NBUCK * 4 + 256;  // pad
    int*   packed       = (int*)w;                 // [E] ints
    __half2* zd         = (__half2*)packed;        // [8N] half2 overlay (32N B <= 4E B)
    w += (size_t)(E > 8 * N ? E : 8 * N) * 4;
    int*   csr      = (int*)w;          w += (size_t)E * 4;
    int*   cnt      = (int*)w;          w += (size_t)N * 4;
    int*   rowStart = (int*)w;          w += (size_t)N * 4;
    float* dinv     = (float*)w;        w += (size_t)N * 4;
    float* u        = (float*)w;        w += (size_t)N * 4;
    float* gsum     = (float*)w;        w += (size_t)16 * G * 4;
    float* cntf     = (float*)w;        w += (size_t)G * 4;
    float* M        = (float*)w;        w += 1024 * 4;
    float* bb       = (float*)w;

    const int chunk = cdiv(E, A2_BLOCKS);

    // CSR build: bucketed counting sort (atomics mostly in LDS)
    k_zero_i<<<1, NBUCK, 0, stream>>>(bucketTot, NBUCK);
    k_bhistA<<<256, 256, 0, stream>>>(dst, bucketTot, E);
    k_bscan<<<1, NBUCK, 0, stream>>>(bucketTot, bucketBase, bucketCursor);
    k_bscatter<<<A2_BLOCKS, 256, 0, stream>>>(src, dst, bucketCursor, packed, E, chunk);
    k_bucket_csr<<<cdiv(N, 256), 256, 0, stream>>>(bucketBase, packed, x,
                                                   cnt, rowStart, dinv, u, csr, N);

    // folded weights
    k_Mbb<<<1, 1024, 0, stream>>>(W2, Wf, b2, bf, M, bb);

    // layer-1 gather + transform -> zd (half2; overlays packed, now dead)
    k_node<<<cdiv(N, TPB), TPB, 0, stream>>>(rowStart, cnt, csr, u, dinv, W1, b1, M, zd, N);

    // layer-2 gather + pool
    k_zero_f<<<cdiv(16 * G + G, TPB), TPB, 0, stream>>>(gsum, 16 * G + G);
    k_gather_pool<<<cdiv(N, 32), 256, 0, stream>>>(bat, rowStart, cnt, csr, zd, dinv, gsum, cntf, N);

    // finalize
    k_final<<<cdiv(G * 16, TPB), TPB, 0, stream>>>(gsum, cntf, bb, out, G);
}